// Round 2
// baseline (10177.685 us; speedup 1.0000x reference)
//
#include <hip/hip_runtime.h>
#include <stdint.h>

#define NB 1024
#define NT 100
#define NPRED 30
#define NE 512
#define NH 1024
#define NG (3*NH)

typedef unsigned short u16;
typedef unsigned int u32;
typedef u16 u16x4 __attribute__((ext_vector_type(4)));
typedef float f32x4 __attribute__((ext_vector_type(4)));
typedef __bf16 bf16x8 __attribute__((ext_vector_type(8)));

__device__ __forceinline__ u16 f2b(float f){
  u32 u = __float_as_uint(f);
  u = (u + 0x7FFFu + ((u >> 16) & 1u)) >> 16;
  return (u16)u;
}
__device__ __forceinline__ float sig_(float x){ return 1.0f/(1.0f+__expf(-x)); }
__device__ __forceinline__ float tanh_(float x){
  float e = __expf(2.0f*fabsf(x));
  return copysignf(1.0f - 2.0f/(e+1.0f), x);
}

// ---------------- fp32 -> bf16 conversion ----------------
__global__ void cvt_kernel(const float* src, u16* dst, int n4){
  int i = blockIdx.x*256 + threadIdx.x;
  if (i < n4){
    f32x4 v = ((const f32x4*)src)[i];
    u16x4 o;
    o[0]=f2b(v[0]); o[1]=f2b(v[1]); o[2]=f2b(v[2]); o[3]=f2b(v[3]);
    ((u16x4*)dst)[i] = o;
  }
}

// ---------------- per-step input embedding (K=2, trivial) ----------------
__global__ void emb_kernel(const float* __restrict__ obs, const float* __restrict__ Wei,
                           const float* __restrict__ bei, u16* __restrict__ out, int t){
  int idx = blockIdx.x*256 + threadIdx.x;      // over NB*NE
  int b = idx >> 9, e = idx & 511;
  float x0 = obs[(b*NT + t)*2], x1 = obs[(b*NT + t)*2 + 1];
  out[idx] = f2b(tanh_(Wei[e*2]*x0 + Wei[e*2+1]*x1 + bei[e]));
}

__global__ void demb_kernel(const float* __restrict__ last, const float* __restrict__ Wed,
                            const float* __restrict__ bed, u16* __restrict__ out){
  int idx = blockIdx.x*256 + threadIdx.x;      // over NB*NE
  int b = idx >> 9, e = idx & 511;
  out[idx] = f2b(tanh_(Wed[e*2]*last[b*2] + Wed[e*2+1]*last[b*2+1] + bed[e]));
}

// ---------------- dual bf16 GEMM: C[z] = A[z] (MxK) * W[z]^T (NxK) + bias[z] ----------------
// M=1024 fixed, N=3072 fixed. 128x128 tile, 4 waves (2x2), 16x16x32 MFMA, BK=32.
__device__ __forceinline__ void gload16(const u16* g, const u16* lds){
  __builtin_amdgcn_global_load_lds(
      (const __attribute__((address_space(1))) void*)g,
      (__attribute__((address_space(3))) void*)lds, 16, 0, 0);
}

__global__ __launch_bounds__(256)
void gemm_dual_kernel(
  const u16* A0, int lda0, int K0, const u16* W0, const float* bias0, float* C0,
  const u16* A1, int lda1, int K1, const u16* W1, const float* bias1, float* C1)
{
  const u16* A; const u16* W; const float* bias; float* C; int lda, K;
  if (blockIdx.z == 0){ A=A0; lda=lda0; K=K0; W=W0; bias=bias0; C=C0; }
  else                { A=A1; lda=lda1; K=K1; W=W1; bias=bias1; C=C1; }

  __shared__ __align__(16) u16 As[128][32];
  __shared__ __align__(16) u16 Bs[128][32];

  const int bRow = blockIdx.y * 128;
  const int bCol = blockIdx.x * 128;
  const int tid = threadIdx.x;
  const int w = tid >> 6, l = tid & 63;
  const int wm = w >> 1, wn = w & 1;          // 2x2 waves -> 64x64 per wave
  const int lrow = l >> 2, lcol = (l & 3) * 8; // staging: 16B per lane
  const int fr = l & 15, fk = (l >> 4) * 8;    // fragment row + k offset

  f32x4 acc[4][4];
  #pragma unroll
  for (int m=0;m<4;m++)
    #pragma unroll
    for (int n=0;n<4;n++) acc[m][n] = (f32x4)0.0f;

  const u16* Ab = A + (size_t)(bRow + lrow)*lda + lcol;
  const u16* Wb = W + (size_t)(bCol + lrow)*K   + lcol;

  for (int k0 = 0; k0 < K; k0 += 32){
    #pragma unroll
    for (int c=0;c<2;c++){
      int r0 = w*32 + c*16;   // wave-uniform 16-row slab (1024B)
      gload16(Ab + (size_t)r0*lda + k0, &As[r0][0]);
      gload16(Wb + (size_t)r0*K   + k0, &Bs[r0][0]);
    }
    __syncthreads();

    bf16x8 af[4], bfr[4];
    #pragma unroll
    for (int m=0;m<4;m++) af[m]  = *(const bf16x8*)&As[wm*64 + m*16 + fr][fk];
    #pragma unroll
    for (int n=0;n<4;n++) bfr[n] = *(const bf16x8*)&Bs[wn*64 + n*16 + fr][fk];

    #pragma unroll
    for (int m=0;m<4;m++)
      #pragma unroll
      for (int n=0;n<4;n++)
        acc[m][n] = __builtin_amdgcn_mfma_f32_16x16x32_bf16(af[m], bfr[n], acc[m][n], 0, 0, 0);

    __syncthreads();
  }

  // epilogue: C/D layout col = lane&15, row = (lane>>4)*4 + reg  [m89/m91 verified]
  const int crow = (l >> 4) * 4, ccol = l & 15;
  #pragma unroll
  for (int n=0;n<4;n++){
    int col = bCol + wn*64 + n*16 + ccol;
    float bv = bias[col];
    #pragma unroll
    for (int m=0;m<4;m++){
      int row = bRow + wm*64 + m*16 + crow;
      float* Cp = C + (size_t)row*NG + col;
      #pragma unroll
      for (int r=0;r<4;r++) Cp[(size_t)r*NG] = acc[m][n][r] + bv;
    }
  }
}

// ---------------- GRU cell: r,z,n gates + state update (memory-bound) ----------------
// seq (optional): per-step (B,H) bf16 slot, same linear index as hout.
__global__ void gru_cell_kernel(const float* __restrict__ gx, const float* __restrict__ gh,
                                const float* __restrict__ hin, float* __restrict__ hout,
                                u16* __restrict__ houtb, u16* __restrict__ seq)
{
  int idx = blockIdx.x*256 + threadIdx.x;   // over NB*NH/4
  int b = idx >> 8, jq = idx & 255;         // NH/4 = 256
  int base = b*768;                         // 3H/4
  const f32x4* gx4 = (const f32x4*)gx;
  const f32x4* gh4 = (const f32x4*)gh;
  f32x4 xr = gx4[base + jq], xz = gx4[base + 256 + jq], xn = gx4[base + 512 + jq];
  f32x4 hr = gh4[base + jq], hz = gh4[base + 256 + jq], hn = gh4[base + 512 + jq];
  f32x4 hv = ((const f32x4*)hin)[idx];
  f32x4 o; u16x4 ob;
  #pragma unroll
  for (int c=0;c<4;c++){
    float r = sig_(xr[c] + hr[c]);
    float z = sig_(xz[c] + hz[c]);
    float n = tanh_(xn[c] + r*hn[c]);
    float h = (1.0f - z)*n + z*hv[c];
    o[c] = h; ob[c] = f2b(h);
  }
  ((f32x4*)hout)[idx] = o;
  ((u16x4*)houtb)[idx] = ob;
  if (seq) ((u16x4*)seq)[idx] = ob;
}

// ---------------- output projection: (B,H) @ Wout^T (2,H) + bout ----------------
__global__ void outproj_kernel(const float* __restrict__ h, const float* __restrict__ Wout,
                               const float* __restrict__ bout, float* __restrict__ last,
                               float* __restrict__ dout, int t)
{
  int b = blockIdx.x, tid = threadIdx.x;
  float s0 = 0.f, s1 = 0.f;
  const float* hb_ = h + (size_t)b*NH;
  for (int j = tid; j < NH; j += 256){
    float hv = hb_[j];
    s0 += hv * Wout[j];
    s1 += hv * Wout[NH + j];
  }
  #pragma unroll
  for (int off = 32; off > 0; off >>= 1){
    s0 += __shfl_down(s0, off);
    s1 += __shfl_down(s1, off);
  }
  __shared__ float red[8];
  int w = tid >> 6;
  if ((tid & 63) == 0){ red[w*2] = s0; red[w*2+1] = s1; }
  __syncthreads();
  if (tid == 0){
    float o0 = red[0]+red[2]+red[4]+red[6] + bout[0];
    float o1 = red[1]+red[3]+red[5]+red[7] + bout[1];
    last[b*2]   = o0;
    last[b*2+1] = o1;
    if (dout){ dout[(size_t)b*(NPRED*2) + t*2]     = o0;
               dout[(size_t)b*(NPRED*2) + t*2 + 1] = o1; }
  }
}

extern "C" void kernel_launch(void* const* d_in, const int* in_sizes, int n_in,
                              void* d_out, int out_size, void* d_ws, size_t ws_size,
                              hipStream_t stream)
{
  (void)in_sizes; (void)n_in; (void)out_size;
  const float* obs  = (const float*)d_in[0];
  const float* We   = (const float*)d_in[1];
  const float* be   = (const float*)d_in[2];
  const float* Wed  = (const float*)d_in[3];
  const float* bed  = (const float*)d_in[4];
  const float* e1Wih = (const float*)d_in[5];
  const float* e1Whh = (const float*)d_in[6];
  const float* e1bih = (const float*)d_in[7];
  const float* e1bhh = (const float*)d_in[8];
  const float* e2Wih = (const float*)d_in[9];
  const float* e2Whh = (const float*)d_in[10];
  const float* e2bih = (const float*)d_in[11];
  const float* e2bhh = (const float*)d_in[12];
  const float* d1Wih = (const float*)d_in[13];
  const float* d1Whh = (const float*)d_in[14];
  const float* d1bih = (const float*)d_in[15];
  const float* d1bhh = (const float*)d_in[16];
  const float* d2Wih = (const float*)d_in[17];
  const float* d2Whh = (const float*)d_in[18];
  const float* d2bih = (const float*)d_in[19];
  const float* d2bhh = (const float*)d_in[20];
  const float* Wout = (const float*)d_in[21];
  const float* bout = (const float*)d_in[22];
  float* out = (float*)d_out;

  // ---- ws_size-adaptive workspace layout (base ~80 MB; enc1 cache sized to fit) ----
  char* ws = (char*)d_ws;
  size_t off = 0;
  auto alloc = [&](size_t bytes)->char* {
    char* p = ws + off;
    off += (bytes + 255) & ~(size_t)255;
    return p;
  };
  u16* wE1i = (u16*)alloc((size_t)NG*NE*2);
  u16* wE1h = (u16*)alloc((size_t)NG*NH*2);
  u16* wE2i = (u16*)alloc((size_t)NG*NH*2);
  u16* wE2h = (u16*)alloc((size_t)NG*NH*2);
  u16* wD1i = (u16*)alloc((size_t)NG*NE*2);
  u16* wD1h = (u16*)alloc((size_t)NG*NH*2);
  u16* wD2i = (u16*)alloc((size_t)NG*NH*2);
  u16* wD2h = (u16*)alloc((size_t)NG*NH*2);
  u16* embb  = (u16*)alloc((size_t)NB*NE*2);
  float* h1f = (float*)alloc((size_t)NB*NH*4);   // GRU1 / decoder-intermediate state (fp32 master)
  u16*   h1b = (u16*)alloc((size_t)NB*NH*2);
  float* h2f = (float*)alloc((size_t)NB*NH*4);   // GRU2 / decoder carry state
  u16*   h2b = (u16*)alloc((size_t)NB*NH*2);
  float* gx  = (float*)alloc((size_t)NB*NG*4);
  float* gh  = (float*)alloc((size_t)NB*NG*4);
  float* last = (float*)alloc((size_t)NB*2*4);

  // enc1 cache: as many TRAILING steps as fit; prefix is recomputed in pass 2.
  const size_t slot_bytes = (size_t)NB*NH*2;     // 2 MB per step
  size_t avail = (ws_size > off + (1u<<20)) ? (ws_size - off - (1u<<20)) : 0;
  int cache_steps = (int)(avail / slot_bytes);
  if (cache_steps > NT) cache_steps = NT;
  u16* cache = (u16*)alloc((size_t)cache_steps * slot_bytes);
  const int cache_start = NT - cache_steps;

  // ---- init ----
  hipMemsetAsync(h1f, 0, (size_t)NB*NH*4, stream);
  hipMemsetAsync(h1b, 0, (size_t)NB*NH*2, stream);

  auto cvt = [&](const float* src, u16* dst, size_t n){
    int n4 = (int)(n >> 2);
    cvt_kernel<<<dim3((n4 + 255)/256), dim3(256), 0, stream>>>(src, dst, n4);
  };
  cvt(e1Wih, wE1i, (size_t)NG*NE);
  cvt(e1Whh, wE1h, (size_t)NG*NH);
  cvt(e2Wih, wE2i, (size_t)NG*NH);
  cvt(e2Whh, wE2h, (size_t)NG*NH);
  cvt(d1Wih, wD1i, (size_t)NG*NE);
  cvt(d1Whh, wD1h, (size_t)NG*NH);
  cvt(d2Wih, wD2i, (size_t)NG*NH);
  cvt(d2Whh, wD2h, (size_t)NG*NH);

  const dim3 gemm_grid(NG/128, NB/128, 2);   // 24 x 8 x 2
  const dim3 blk(256);
  const dim3 emb_grid((NB*NE)/256);          // 2048
  const dim3 cell_grid((NB*NH/4)/256);       // 1024

  // ---- pass 1: GRU1 over all T (stores trailing cache_steps outputs) ----
  for (int t = 0; t < NT; ++t){
    emb_kernel<<<emb_grid, blk, 0, stream>>>(obs, We, be, embb, t);
    gemm_dual_kernel<<<gemm_grid, blk, 0, stream>>>(
        embb, NE, NE, wE1i, e1bih, gx,
        h1b,  NH, NH, wE1h, e1bhh, gh);
    u16* slot = (t >= cache_start) ? cache + (size_t)(t - cache_start)*NB*NH : (u16*)nullptr;
    gru_cell_kernel<<<cell_grid, blk, 0, stream>>>(gx, gh, h1f, h1f, h1b, slot);
  }

  // GRU2 initial hidden = GRU1 final hidden (the reference quirk)
  hipMemcpyAsync(h2f, h1f, (size_t)NB*NH*4, hipMemcpyDeviceToDevice, stream);
  hipMemcpyAsync(h2b, h1b, (size_t)NB*NH*2, hipMemcpyDeviceToDevice, stream);

  // ---- pass 2: GRU2 over all T; recompute GRU1 prefix where not cached ----
  hipMemsetAsync(h1f, 0, (size_t)NB*NH*4, stream);
  hipMemsetAsync(h1b, 0, (size_t)NB*NH*2, stream);
  for (int t = 0; t < NT; ++t){
    const u16* enc1_t;
    if (t < cache_start){
      emb_kernel<<<emb_grid, blk, 0, stream>>>(obs, We, be, embb, t);
      gemm_dual_kernel<<<gemm_grid, blk, 0, stream>>>(
          embb, NE, NE, wE1i, e1bih, gx,
          h1b,  NH, NH, wE1h, e1bhh, gh);
      gru_cell_kernel<<<cell_grid, blk, 0, stream>>>(gx, gh, h1f, h1f, h1b, (u16*)nullptr);
      enc1_t = h1b;
    } else {
      enc1_t = cache + (size_t)(t - cache_start)*NB*NH;
    }
    gemm_dual_kernel<<<gemm_grid, blk, 0, stream>>>(
        enc1_t, NH, NH, wE2i, e2bih, gx,
        h2b,    NH, NH, wE2h, e2bhh, gh);
    gru_cell_kernel<<<cell_grid, blk, 0, stream>>>(gx, gh, h2f, h2f, h2b, (u16*)nullptr);
    if (t == NT - 2){
      outproj_kernel<<<dim3(NB), blk, 0, stream>>>(h2f, Wout, bout, last, (float*)nullptr, 0);
    }
  }

  // ---- autoregressive decoder (carry = h2, intermediate = h1) ----
  for (int t = 0; t < NPRED; ++t){
    demb_kernel<<<emb_grid, blk, 0, stream>>>(last, Wed, bed, embb);
    gemm_dual_kernel<<<gemm_grid, blk, 0, stream>>>(
        embb, NE, NE, wD1i, d1bih, gx,
        h2b,  NH, NH, wD1h, d1bhh, gh);
    gru_cell_kernel<<<cell_grid, blk, 0, stream>>>(gx, gh, h2f, h1f, h1b, (u16*)nullptr);
    gemm_dual_kernel<<<gemm_grid, blk, 0, stream>>>(
        h1b, NH, NH, wD2i, d2bih, gx,
        h1b, NH, NH, wD2h, d2bhh, gh);
    gru_cell_kernel<<<cell_grid, blk, 0, stream>>>(gx, gh, h1f, h2f, h2b, (u16*)nullptr);
    outproj_kernel<<<dim3(NB), blk, 0, stream>>>(h2f, Wout, bout, last, out, t);
  }
}